// Round 4
// baseline (477.634 us; speedup 1.0000x reference)
//
#include <hip/hip_runtime.h>

#define NG 40

// ---------- pre-kernel: K2[g] = k[g] (full 2-D conv) k[g], 9x9 per group ----------
// Two circular cross-correlations with k == one circular cross-correlation with K2.
__global__ void compose_k2(const float* __restrict__ kernels, float* __restrict__ k2) {
    int t = blockIdx.x * 256 + threadIdx.x;          // 40*81 = 3240 outputs
    if (t >= NG * 81) return;
    int gi = t / 81, r = t - gi * 81;
    int a = r / 9, b = r - a * 9;
    const float* k = kernels + gi * 25;
    float s = 0.f;
    for (int i = 0; i < 5; ++i) {
        int p = a - i;
        if (p < 0 || p > 4) continue;
        for (int j = 0; j < 5; ++j) {
            int q = b - j;
            if (q < 0 || q > 4) continue;
            s += k[i * 5 + j] * k[p * 5 + q];
        }
    }
    k2[t] = s;
}

// ---------- main kernel: one 56x56 plane per block, NO LDS TILE ----------
// Rounds 0-2 showed all LDS-tile layouts pay a large, layout-insensitive
// bank-conflict tax (1.2-1.9e7) on this read shape, and the tile caps
// occupancy at ~28%. But a plane is only 12.5 KB: it fits L1. Column
// overlap (3 lanes share a 16B line IN THE SAME instruction -> one L1
// access, broadcast) and row overlap (15/7 rows, same block) are served
// by L1/L2, so direct global reads cost ~1x HBM fetch and the L1 service
// time sits under the ~30 us FMA floor. Deleting the tile removes staging,
// the barrier, all LDS reads/conflicts, and the LDS occupancy cap.
//
// (Round 3 was an infra failure — "container failed twice", no kernel
// verdict. Re-running the same structure; only change: waves hint 6->4.)
//
// Thread (rg = tid>>4, pc = tid&15): outputs rows 7*rg..7*rg+6, cols
// 4*pc..4*pc+3 (pc=14,15 compute discarded duplicates, skip the store).
template <bool USE_WS>
__global__ __launch_bounds__(128, 4)
void conv9_direct(const float* __restrict__ x, const float* __restrict__ kdata,
                  const int* __restrict__ g, float* __restrict__ out) {
    const int tid = threadIdx.x;
    const int bx  = blockIdx.x;          // == b*64 + channel, 8192 blocks
    const int b   = bx >> 6;

    int gi = g[b] % NG; if (gi < 0) gi += NG;

    // --- composed 9x9 taps ---
    float kk[81];
    if constexpr (USE_WS) {
        const float* kp = kdata + gi * 81;   // wave-uniform address -> SGPRs
        #pragma unroll
        for (int i = 0; i < 81; ++i) kk[i] = kp[i];
    } else {
        __shared__ float k9s[84];            // tiny; fallback path only
        if (tid < 81) {
            const float* k = kdata + gi * 25;
            int a = tid / 9, bb = tid - a * 9;
            float s = 0.f;
            for (int i = 0; i < 5; ++i) {
                int p = a - i;
                if (p < 0 || p > 4) continue;
                for (int j = 0; j < 5; ++j) {
                    int q = bb - j;
                    if (q < 0 || q > 4) continue;
                    s += k[i * 5 + j] * k[p * 5 + q];
                }
            }
            k9s[tid] = s;
        }
        __syncthreads();
        #pragma unroll
        for (int i = 0; i < 81; ++i) kk[i] = k9s[i];
    }

    const int rg = tid >> 4;             // 0..7  -> q = 7*rg
    const int pc = tid & 15;             // 0..15 -> c = 4*pc (14,15 discarded)
    const int q  = 7 * rg;
    const int c  = 4 * pc;

    // circular column base offsets (floats), each a contiguous 16B-aligned run
    int c0 = c - 4; if (c0 < 0) c0 += 56; if (c0 >= 56) c0 -= 56;
    int c1 = c;     if (c1 >= 56) c1 -= 56;
    int c2 = c + 4; if (c2 >= 56) c2 -= 56;

    const float* xp = x + (size_t)bx * 3136;
    int r = q - 4; if (r < 0) r += 56;   // circular starting row

    float acc[7][4] = {};

    #pragma unroll
    for (int h = 0; h < 15; ++h) {
        const float* rp = xp + r * 56;
        float4 A = *(const float4*)(rp + c0);
        float4 B = *(const float4*)(rp + c1);
        float4 C = *(const float4*)(rp + c2);
        ++r; if (r == 56) r = 0;
        float w[12] = {A.x, A.y, A.z, A.w, B.x, B.y, B.z, B.w, C.x, C.y, C.z, C.w};
        #pragma unroll
        for (int ro = 0; ro < 7; ++ro) {
            const int v = h - ro;         // kernel row tap
            if (v < 0 || v > 8) continue; // folded at compile time
            #pragma unroll
            for (int j = 0; j < 4; ++j) {
                #pragma unroll
                for (int u = 0; u < 9; ++u)
                    acc[ro][j] += w[j + u] * kk[v * 9 + u];
            }
        }
    }

    if (pc < 14) {
        float* op = out + (size_t)bx * 3136 + q * 56 + c;
        #pragma unroll
        for (int ro = 0; ro < 7; ++ro)
            *(float4*)(op + ro * 56) =
                make_float4(acc[ro][0], acc[ro][1], acc[ro][2], acc[ro][3]);
    }
}

extern "C" void kernel_launch(void* const* d_in, const int* in_sizes, int n_in,
                              void* d_out, int out_size, void* d_ws, size_t ws_size,
                              hipStream_t stream) {
    const float* x    = (const float*)d_in[0];
    const float* kern = (const float*)d_in[1];
    const int*   g    = (const int*)d_in[2];
    float*       out  = (float*)d_out;

    const bool use_ws = ws_size >= (size_t)(NG * 81 * sizeof(float));
    if (use_ws) {
        compose_k2<<<dim3((NG * 81 + 255) / 256), dim3(256), 0, stream>>>(kern, (float*)d_ws);
        conv9_direct<true><<<dim3(8192), dim3(128), 0, stream>>>(x, (const float*)d_ws, g, out);
    } else {
        conv9_direct<false><<<dim3(8192), dim3(128), 0, stream>>>(x, kern, g, out);
    }
}

// Round 5
// 213.681 us; speedup vs baseline: 2.2353x; 2.2353x over previous
//
#include <hip/hip_runtime.h>

#define NG 40

// ---------- pre-kernel: K2[g] = k[g] (full 2-D conv) k[g], 9x9 per group ----------
__global__ void compose_k2(const float* __restrict__ kernels, float* __restrict__ k2) {
    int t = blockIdx.x * 256 + threadIdx.x;          // 40*81 = 3240 outputs
    if (t >= NG * 81) return;
    int gi = t / 81, r = t - gi * 81;
    int a = r / 9, b = r - a * 9;
    const float* k = kernels + gi * 25;
    float s = 0.f;
    for (int i = 0; i < 5; ++i) {
        int p = a - i;
        if (p < 0 || p > 4) continue;
        for (int j = 0; j < 5; ++j) {
            int q = b - j;
            if (q < 0 || q > 4) continue;
            s += k[i * 5 + j] * k[p * 5 + q];
        }
    }
    k2[t] = s;
}

// ---------- main kernel: one 56x56 plane per block ----------
// Layout: 64 padded rows x 66-float stride (264B). Why 66:
//   b128 reads are PROVABLY >=8-way bank-conflicted here (phase model: bank =
//   4*(seg class mod 8) + w; 64 lanes / 8 classes = 8, invariant under any
//   16B-granular swizzle — this is why r1/r2 layout changes failed).
//   b64 reads have a 4-way floor, reached when stride mod 32 words != 0:
//   stride 66 floats -> per phase banks (14*rg + 4*pc + C) mod 32, rg-cosets
//   {0,14,28,10} spread mod 4 -> uniform <=4-way (~1.58x) vs measured ~3x tax.
// Staging: stride 66 has non-integral 16B rows -> global_load_lds can't fill;
//   reg-stage instead (9 dwordx4 loads + 18 ds_write_b64, one-time).
// Hot loop: 90 ds_read_b64, ALL folded to one base reg + offset immediates
//   (max 4220*4 B < 64KiB) -> zero address VALU in loop (r1's mistake avoided).
// Lanes pc=14,15 read pc-0/1's exact addresses (same-address broadcast = free)
//   and discard their stores.
template <bool USE_WS>
__global__ __launch_bounds__(128, 4)
void conv9_main(const float* __restrict__ x, const float* __restrict__ kdata,
                const int* __restrict__ g, float* __restrict__ out) {
    __shared__ float tile[64 * 66 + 4];
    __shared__ float k9s[84];

    const int tid = threadIdx.x;
    const int bx  = blockIdx.x;          // == b*64 + channel, 8192 blocks
    const int b   = bx >> 6;

    int gi = g[b] % NG; if (gi < 0) gi += NG;

    // --- stage plane: global -> regs (MLP: all 8 loads in flight) -> LDS ---
    const float* xp = x + (size_t)bx * 3136;
    float4 stg[8];
    #pragma unroll
    for (int m = 0; m < 8; ++m) {
        int idx = m * 128 + tid;         // 0..1023 = padded row*16 + seg
        int pr  = idx >> 4;
        int seg = idx & 15;
        int sr = pr - 4;      if (sr < 0) sr += 56; if (sr >= 56) sr -= 56;
        int sc = seg * 4 - 4; if (sc < 0) sc += 56; if (sc >= 56) sc -= 56;
        stg[m] = *(const float4*)(xp + sr * 56 + sc);
    }
    #pragma unroll
    for (int m = 0; m < 8; ++m) {
        int idx = m * 128 + tid;
        int pr  = idx >> 4;
        int seg = idx & 15;
        float* d = tile + pr * 66 + seg * 4;      // 8B-aligned (66*pr+4*seg even)
        *(float2*)(d)       = make_float2(stg[m].x, stg[m].y);
        *(float2*)(d + 2)   = make_float2(stg[m].z, stg[m].w);
    }

    // --- composed 9x9 taps ---
    float kk[81];
    if constexpr (USE_WS) {
        const float* kp = kdata + gi * 81;   // wave-uniform address -> scalar loads
        #pragma unroll
        for (int i = 0; i < 81; ++i) kk[i] = kp[i];
    } else {
        if (tid < 81) {
            const float* k = kdata + gi * 25;
            int a = tid / 9, bb = tid - a * 9;
            float s = 0.f;
            for (int i = 0; i < 5; ++i) {
                int p = a - i;
                if (p < 0 || p > 4) continue;
                for (int j = 0; j < 5; ++j) {
                    int q = bb - j;
                    if (q < 0 || q > 4) continue;
                    s += k[i * 5 + j] * k[p * 5 + q];
                }
            }
            k9s[tid] = s;
        }
    }

    __syncthreads();

    if constexpr (!USE_WS) {
        #pragma unroll
        for (int i = 0; i < 81; ++i) kk[i] = k9s[i];   // broadcast reads
    }

    // --- compute: 8x16 grid, 7-row x 4-col patch each ---
    const int rg = tid >> 4;             // 0..7  -> q = 7*rg
    const int pc = tid & 15;             // 0..15 (14,15 duplicate pc 0,1)
    const int q  = 7 * rg;
    const int pcr = (pc < 14) ? pc : (pc - 14);  // read index: dup lanes broadcast
    const int c  = 4 * pc;

    float acc[7][4] = {};
    const float* trow = tile + q * 66 + 4 * pcr; // padded col 4*pcr = logical 4*pcr-4

    #pragma unroll
    for (int h = 0; h < 15; ++h) {
        const float* rp = trow + h * 66;
        // 12-float window as 6 x ds_read_b64 (8B-aligned; offsets fold)
        float2 w01 = *(const float2*)(rp);
        float2 w23 = *(const float2*)(rp + 2);
        float2 w45 = *(const float2*)(rp + 4);
        float2 w67 = *(const float2*)(rp + 6);
        float2 w89 = *(const float2*)(rp + 8);
        float2 wAB = *(const float2*)(rp + 10);
        float w[12] = {w01.x, w01.y, w23.x, w23.y, w45.x, w45.y,
                       w67.x, w67.y, w89.x, w89.y, wAB.x, wAB.y};
        #pragma unroll
        for (int ro = 0; ro < 7; ++ro) {
            const int v = h - ro;         // kernel row tap
            if (v < 0 || v > 8) continue; // folded at compile time
            #pragma unroll
            for (int j = 0; j < 4; ++j) {
                #pragma unroll
                for (int u = 0; u < 9; ++u)
                    acc[ro][j] += w[j + u] * kk[v * 9 + u];
            }
        }
    }

    if (pc < 14) {
        float* op = out + (size_t)bx * 3136 + q * 56 + c;
        #pragma unroll
        for (int ro = 0; ro < 7; ++ro)
            *(float4*)(op + ro * 56) =
                make_float4(acc[ro][0], acc[ro][1], acc[ro][2], acc[ro][3]);
    }
}

extern "C" void kernel_launch(void* const* d_in, const int* in_sizes, int n_in,
                              void* d_out, int out_size, void* d_ws, size_t ws_size,
                              hipStream_t stream) {
    const float* x    = (const float*)d_in[0];
    const float* kern = (const float*)d_in[1];
    const int*   g    = (const int*)d_in[2];
    float*       out  = (float*)d_out;

    const bool use_ws = ws_size >= (size_t)(NG * 81 * sizeof(float));
    if (use_ws) {
        compose_k2<<<dim3((NG * 81 + 255) / 256), dim3(256), 0, stream>>>(kern, (float*)d_ws);
        conv9_main<true><<<dim3(8192), dim3(128), 0, stream>>>(x, (const float*)d_ws, g, out);
    } else {
        conv9_main<false><<<dim3(8192), dim3(128), 0, stream>>>(x, kern, g, out);
    }
}